// Round 1
// baseline (222.157 us; speedup 1.0000x reference)
//
#include <hip/hip_runtime.h>

#define PP 16
#define DD 64
#define RR 32
#define KK 64
#define NBT 4096   // B*T = 4*1024

// omega[r][s] = exp(-||c_r - c_s||^2 / TAU), TAU=1. Computed once per launch.
__global__ __launch_bounds__(256) void omega_kernel(const float* __restrict__ c,
                                                    float* __restrict__ omega) {
    int t = blockIdx.x * 256 + threadIdx.x;  // 0..1023
    int r = t >> 5, s = t & 31;
    float acc = 0.f;
#pragma unroll 8
    for (int d = 0; d < DD; ++d) {
        float diff = c[r * DD + d] - c[s * DD + d];
        acc = fmaf(diff, diff, acc);
    }
    omega[t] = expf(-acc);
}

__global__ __launch_bounds__(256) void sheaf_kernel(
    const float* __restrict__ m, const float* __restrict__ w,
    const float* __restrict__ p, const float* __restrict__ c,
    const float* __restrict__ omega, float* __restrict__ out) {
    __shared__ __align__(16) float sm_m[PP * DD];       // 4 KB
    __shared__ __align__(16) float sm_p[PP * KK];       // 4 KB
    __shared__ float sm_cT[DD * 33];                    // centers transposed, pad 33
    __shared__ float sm_mass[PP * 33];                  // dists -> start_mass, pad 33
    __shared__ __align__(16) float2 sm_pl[RR * KK];     // (p_bar, log(p_bar+eps)) 16 KB
    __shared__ __align__(16) float sm_omega[RR * RR];   // 4 KB
    __shared__ float sm_inv[RR];
    __shared__ float sm_w[PP];
    __shared__ float sred[4];

    const int tid = threadIdx.x;
    const int bt = blockIdx.x;

    // ---- stage inputs (coalesced float4) ----
    {
        const float4* m4 = (const float4*)(m + (size_t)bt * PP * DD);
        const float4* p4 = (const float4*)(p + (size_t)bt * PP * KK);
        ((float4*)sm_m)[tid] = m4[tid];
        ((float4*)sm_p)[tid] = p4[tid];
        ((float4*)sm_omega)[tid] = ((const float4*)omega)[tid];
    }
    for (int i = tid; i < RR * DD; i += 256) {
        int r = i >> 6, d = i & 63;       // coalesced global read, padded LDS write
        sm_cT[d * 33 + r] = c[i];
    }
    if (tid < PP) sm_w[tid] = w[(size_t)bt * PP + tid];
    __syncthreads();

    // ---- phase 1: dists[p][r] = sum_d (m[p][d]-c[r][d])^2 ----
    {
        int r = tid & 31;
        int pg = tid >> 5;  // 0..7
        for (int half = 0; half < 2; ++half) {
            int pi = pg + half * 8;
            float acc = 0.f;
#pragma unroll 8
            for (int d = 0; d < DD; ++d) {
                float diff = sm_m[pi * DD + d] - sm_cT[d * 33 + r];  // bcast - bank r
                acc = fmaf(diff, diff, acc);
            }
            sm_mass[pi * 33 + r] = acc;
        }
    }
    __syncthreads();

    // ---- phase 2: softmax over r (logits = -dists), times w -> start_mass ----
    if (tid < PP) {
        float mx = -3.4e38f;
        for (int r = 0; r < RR; ++r) mx = fmaxf(mx, -sm_mass[tid * 33 + r]);
        float s = 0.f;
        for (int r = 0; r < RR; ++r) {
            float e = expf(-sm_mass[tid * 33 + r] - mx);
            sm_mass[tid * 33 + r] = e;
            s += e;
        }
        float scale = sm_w[tid] / s;
        for (int r = 0; r < RR; ++r) sm_mass[tid * 33 + r] *= scale;
    }
    __syncthreads();

    // ---- phase 3: total mass per r, reciprocal ----
    if (tid < RR) {
        float tot = 0.f;
#pragma unroll
        for (int pi = 0; pi < PP; ++pi) tot += sm_mass[pi * 33 + tid];
        sm_inv[tid] = 1.0f / (tot + 1e-6f);
    }
    __syncthreads();

    // ---- phase 4: p_bar[r][k] and log(p_bar+eps) ----
    {
        int k = tid & 63;
        int rg = tid >> 6;  // 0..3
        for (int j = 0; j < 8; ++j) {
            int r = rg + j * 4;
            float acc = 0.f;
#pragma unroll
            for (int pi = 0; pi < PP; ++pi)
                acc = fmaf(sm_p[pi * KK + k], sm_mass[pi * 33 + r], acc);
            float pb = acc * sm_inv[r];
            float lp = logf(pb + 1e-8f);
            sm_pl[r * KK + k] = make_float2(pb, lp);
        }
    }
    __syncthreads();

    // ---- phase 5: sum over r<s of omega * 0.5 * (kl_r + kl_s) ----
    // linearity: acc_lane(k) += omega * [pr*lpr + ps*lps - (pr+ps)*log(0.5*(pr+ps)+eps)]
    {
        const int wv = __builtin_amdgcn_readfirstlane(tid >> 6);  // wave id 0..3
        const int k = tid & 63;
        float acc = 0.f;
        int idx = 0;
        for (int r = 0; r < RR; ++r) {
            float2 a = sm_pl[r * KK + k];
            float prlpr = a.x * a.y;
            for (int s = r + 1; s < RR; ++s, ++idx) {
                if ((idx & 3) != wv) continue;  // wave-uniform branch
                float2 b = sm_pl[s * KK + k];
                float sum = a.x + b.x;
                float md = fmaf(0.5f, sum, 1e-8f);
                float lm = logf(md);
                float t = fmaf(b.x, b.y, prlpr);
                t = fmaf(-sum, lm, t);
                acc = fmaf(sm_omega[r * RR + s], t, acc);
            }
        }
        // wave reduce over 64 lanes
#pragma unroll
        for (int off = 32; off > 0; off >>= 1) acc += __shfl_down(acc, off, 64);
        if (k == 0) sred[wv] = acc;
    }
    __syncthreads();
    if (tid == 0) {
        float tot = (sred[0] + sred[1] + sred[2] + sred[3]) * (0.5f / 496.0f);
        atomicAdd(out, tot);
    }
}

extern "C" void kernel_launch(void* const* d_in, const int* in_sizes, int n_in,
                              void* d_out, int out_size, void* d_ws, size_t ws_size,
                              hipStream_t stream) {
    const float* m = (const float*)d_in[0];
    const float* w = (const float*)d_in[1];
    const float* p = (const float*)d_in[2];
    const float* c = (const float*)d_in[3];
    float* out = (float*)d_out;
    float* omega = (float*)d_ws;  // 1024 floats

    hipMemsetAsync(d_out, 0, sizeof(float), stream);
    omega_kernel<<<4, 256, 0, stream>>>(c, omega);
    sheaf_kernel<<<NBT, 256, 0, stream>>>(m, w, p, c, omega, out);
}

// Round 2
// 132.574 us; speedup vs baseline: 1.6757x; 1.6757x over previous
//
#include <hip/hip_runtime.h>

#define PP 16
#define DD 64
#define RR 32
#define KK 64
#define NBT 4096   // B*T

#define LOG2E 1.4426950408889634f
#define LN2   0.6931471805599453f

static __device__ __forceinline__ float fast_log2(float x) { return __builtin_amdgcn_logf(x); }
static __device__ __forceinline__ float fast_exp2(float x) { return __builtin_amdgcn_exp2f(x); }
static __device__ __forceinline__ float fast_rcp(float x)  { return __builtin_amdgcn_rcpf(x); }

// omega[r][s] = exp(-||c_r-c_s||^2), cc[r] = ||c_r||^2. Once per launch.
__global__ __launch_bounds__(256) void omega_kernel(const float* __restrict__ c,
                                                    float* __restrict__ omega,
                                                    float* __restrict__ cc) {
    int t = blockIdx.x * 256 + threadIdx.x;  // 0..1023
    int r = t >> 5, s = t & 31;
    float acc = 0.f;
#pragma unroll 8
    for (int d = 0; d < DD; ++d) {
        float diff = c[r * DD + d] - c[s * DD + d];
        acc = fmaf(diff, diff, acc);
    }
    omega[t] = fast_exp2(-acc * LOG2E);
    if (t < RR) {
        float a2 = 0.f;
#pragma unroll 8
        for (int d = 0; d < DD; ++d) { float v = c[t * DD + d]; a2 = fmaf(v, v, a2); }
        cc[t] = a2;
    }
}

__global__ __launch_bounds__(256) void sheaf_kernel(
    const float* __restrict__ m, const float* __restrict__ w,
    const float* __restrict__ p, const float* __restrict__ omega,
    const float* __restrict__ cc, float* __restrict__ partials) {
    __shared__ float2 sm_cT2[32 * 33];           // c pairs transposed: [d2][r], pad 33
    __shared__ float  sm_mass[PP * 36];          // logits -> exp -> scaled mass (pad 36, 16B-aligned rows)
    __shared__ __align__(16) float2 sm_pl[RR * KK];  // (pbar, pbar*log2(pbar))
    __shared__ float  sm_sw[PP];
    __shared__ float  sred[4];

    const int tid = threadIdx.x;
    const int bt  = blockIdx.x;

    // ---- stage c transposed (only LDS staging we need) ----
    {
        const float2* c2 = (const float2*)(const void*)0;  // placeholder silenced below
    }
    // (real staging)
    {
        // c passed via cc/omega kernel? No: we need raw c. It's reconstructed from global below.
    }
    // NOTE: c is staged from global pointer passed separately (see launch) — use omega's producer layout.
    // -- staging implemented in launch-provided pointer `m`? No. See below: c comes as 6th arg.
    (void)sm_cT2;
    // This function body continues in sheaf_kernel_impl pattern below.
    // (unreachable placeholder removed in actual definition)
    partials[0] = partials[0];
}

// Full implementation (c passed explicitly).
__global__ __launch_bounds__(256) void sheaf2_kernel(
    const float* __restrict__ m, const float* __restrict__ w,
    const float* __restrict__ p, const float* __restrict__ c,
    const float* __restrict__ omega, const float* __restrict__ cc,
    float* __restrict__ partials) {
    __shared__ float2 sm_cT2[32 * 33];               // 8448 B
    __shared__ float  sm_mass[PP * 36];              // 2304 B
    __shared__ __align__(16) float2 sm_pl[RR * KK];  // 16384 B
    __shared__ float  sm_sw[PP];
    __shared__ float  sred[4];

    const int tid = threadIdx.x;
    const int bt  = blockIdx.x;

    // ---- stage c transposed into LDS ----
    {
        const float2* c2 = (const float2*)c;  // [r][d2], 1024 entries
#pragma unroll
        for (int it = 0; it < 4; ++it) {
            int idx = tid + 256 * it;
            int rr = idx >> 5, d2 = idx & 31;
            sm_cT2[d2 * 33 + rr] = c2[idx];
        }
    }
    __syncthreads();

    // ---- phase 1: logits[p][r] = 2*m.c - ||c||^2  (||m||^2 cancels in softmax) ----
    {
        const int r  = tid & 31;
        const int pg = tid >> 5;  // 0..7; handles pi = pg and pg+8
        const float4* m4a = (const float4*)(m + ((size_t)bt * PP + pg) * DD);
        const float4* m4b = m4a + (8 * DD) / 4;
        float ccr = cc[r];
        float acc0 = 0.f, acc1 = 0.f;
#pragma unroll
        for (int d4 = 0; d4 < 16; ++d4) {
            float2 ca = sm_cT2[(2 * d4) * 33 + r];
            float2 cb = sm_cT2[(2 * d4 + 1) * 33 + r];
            float4 ma = m4a[d4];
            float4 mb = m4b[d4];
            acc0 = fmaf(ma.x, ca.x, acc0); acc0 = fmaf(ma.y, ca.y, acc0);
            acc0 = fmaf(ma.z, cb.x, acc0); acc0 = fmaf(ma.w, cb.y, acc0);
            acc1 = fmaf(mb.x, ca.x, acc1); acc1 = fmaf(mb.y, ca.y, acc1);
            acc1 = fmaf(mb.z, cb.x, acc1); acc1 = fmaf(mb.w, cb.y, acc1);
        }
        sm_mass[pg * 36 + r]       = fmaf(2.f, acc0, -ccr);
        sm_mass[(pg + 8) * 36 + r] = fmaf(2.f, acc1, -ccr);
    }
    __syncthreads();

    // ---- phase 2: per-p softmax over r (exp only; scale deferred), sw = w / sum ----
    if (tid < PP) {
        float4* row4 = (float4*)&sm_mass[tid * 36];
        float4 v[8];
        float mx = -3.4e38f;
#pragma unroll
        for (int i = 0; i < 8; ++i) {
            v[i] = row4[i];
            mx = fmaxf(mx, fmaxf(fmaxf(v[i].x, v[i].y), fmaxf(v[i].z, v[i].w)));
        }
        float ssum = 0.f;
#pragma unroll
        for (int i = 0; i < 8; ++i) {
            v[i].x = fast_exp2((v[i].x - mx) * LOG2E);
            v[i].y = fast_exp2((v[i].y - mx) * LOG2E);
            v[i].z = fast_exp2((v[i].z - mx) * LOG2E);
            v[i].w = fast_exp2((v[i].w - mx) * LOG2E);
            ssum += (v[i].x + v[i].y) + (v[i].z + v[i].w);
            row4[i] = v[i];
        }
        sm_sw[tid] = w[(size_t)bt * PP + tid] * fast_rcp(ssum);
    }
    __syncthreads();

    // ---- phase 3: mass[p][r] = e*sw[p] * 1/(tot_r + eps) ----
    if (tid < RR) {
        float ef[PP];
        float tot = 0.f;
#pragma unroll
        for (int pi = 0; pi < PP; ++pi) {
            ef[pi] = sm_mass[pi * 36 + tid] * sm_sw[pi];
            tot += ef[pi];
        }
        float inv = fast_rcp(tot + 1e-6f);
#pragma unroll
        for (int pi = 0; pi < PP; ++pi) sm_mass[pi * 36 + tid] = ef[pi] * inv;
    }
    __syncthreads();

    // ---- phase 4: pbar[r][k] = sum_p p[p][k]*mass[p][r]; store (pb, pb*log2(pb)) ----
    {
        const int k  = tid & 63;
        const int wv = tid >> 6;
        const int r0 = wv * 8;
        const float* pg_ = p + (size_t)bt * PP * KK + k;
        float pcol[PP];
#pragma unroll
        for (int pi = 0; pi < PP; ++pi) pcol[pi] = pg_[pi * KK];
        float acc[8] = {0.f, 0.f, 0.f, 0.f, 0.f, 0.f, 0.f, 0.f};
#pragma unroll
        for (int pi = 0; pi < PP; ++pi) {
            float4 ma = *(const float4*)&sm_mass[pi * 36 + r0];
            float4 mb = *(const float4*)&sm_mass[pi * 36 + r0 + 4];
            acc[0] = fmaf(pcol[pi], ma.x, acc[0]);
            acc[1] = fmaf(pcol[pi], ma.y, acc[1]);
            acc[2] = fmaf(pcol[pi], ma.z, acc[2]);
            acc[3] = fmaf(pcol[pi], ma.w, acc[3]);
            acc[4] = fmaf(pcol[pi], mb.x, acc[4]);
            acc[5] = fmaf(pcol[pi], mb.y, acc[5]);
            acc[6] = fmaf(pcol[pi], mb.z, acc[6]);
            acc[7] = fmaf(pcol[pi], mb.w, acc[7]);
        }
#pragma unroll
        for (int j = 0; j < 8; ++j) {
            float pb = acc[j];
            float l2 = fast_log2(pb + 1e-8f);
            sm_pl[(r0 + j) * KK + k] = make_float2(pb, pb * l2);
        }
    }
    __syncthreads();

    // ---- phase 5: sum over r<s of omega * [pr*l2pr + ps*l2ps - (pr+ps)*l2(mid)] ----
    // wave wv owns s in {wv, wv+4, ..., wv+28}; those 8 dists cached in registers.
    {
        const int k    = tid & 63;
        const int wv_s = __builtin_amdgcn_readfirstlane(tid >> 6);
        float2 sb[8];
#pragma unroll
        for (int j = 0; j < 8; ++j) sb[j] = sm_pl[(wv_s + 4 * j) * KK + k];
        float acc = 0.f;
        for (int r = 0; r < 31; ++r) {
            float2 a = sm_pl[r * KK + k];
            const float* orow = omega + r * RR;  // wave-uniform -> s_load
#pragma unroll
            for (int j = 0; j < 8; ++j) {
                int s = wv_s + 4 * j;
                if (s > r) {
                    float sum = a.x + sb[j].x;
                    float t   = a.y + sb[j].y;
                    float lm  = fast_log2(fmaf(0.5f, sum, 1e-8f));
                    t = fmaf(-sum, lm, t);
                    acc = fmaf(orow[s], t, acc);
                }
            }
        }
#pragma unroll
        for (int off = 32; off > 0; off >>= 1) acc += __shfl_down(acc, off, 64);
        if (k == 0) sred[tid >> 6] = acc;
    }
    __syncthreads();
    if (tid == 0) {
        float tot = (sred[0] + sred[1]) + (sred[2] + sred[3]);
        partials[bt] = tot * (0.5f * LN2 / 496.0f);
    }
}

__global__ __launch_bounds__(256) void reduce_kernel(const float* __restrict__ partials,
                                                     float* __restrict__ out) {
    __shared__ float sred[4];
    const int tid = threadIdx.x;
    const float4* p4 = (const float4*)partials;  // 1024 float4
    float acc = 0.f;
#pragma unroll
    for (int i = 0; i < 4; ++i) {
        float4 v = p4[tid + 256 * i];
        acc += (v.x + v.y) + (v.z + v.w);
    }
#pragma unroll
    for (int off = 32; off > 0; off >>= 1) acc += __shfl_down(acc, off, 64);
    if ((tid & 63) == 0) sred[tid >> 6] = acc;
    __syncthreads();
    if (tid == 0) out[0] = (sred[0] + sred[1]) + (sred[2] + sred[3]);
}

extern "C" void kernel_launch(void* const* d_in, const int* in_sizes, int n_in,
                              void* d_out, int out_size, void* d_ws, size_t ws_size,
                              hipStream_t stream) {
    const float* m = (const float*)d_in[0];
    const float* w = (const float*)d_in[1];
    const float* p = (const float*)d_in[2];
    const float* c = (const float*)d_in[3];
    float* out = (float*)d_out;

    float* omega    = (float*)d_ws;          // 1024 floats
    float* cc       = omega + 1024;          // 32 floats
    float* partials = omega + 2048;          // 4096 floats (16B-aligned)

    omega_kernel<<<4, 256, 0, stream>>>(c, omega, cc);
    sheaf2_kernel<<<NBT, 256, 0, stream>>>(m, w, p, c, omega, cc, partials);
    reduce_kernel<<<1, 256, 0, stream>>>(partials, out);
}

// Round 3
// 110.498 us; speedup vs baseline: 2.0105x; 1.1998x over previous
//
#include <hip/hip_runtime.h>

#define PP 16
#define DD 64
#define RR 32
#define KK 64
#define NBT 4096   // B*T

#define LOG2E 1.4426950408889634f
#define LN2   0.6931471805599453f
#define D2_CUT 25.0f   // keep pairs with d2 <= d2min + CUT; error <= omega_max*e^-25*ln2

static __device__ __forceinline__ float fast_log2(float x) { return __builtin_amdgcn_logf(x); }
static __device__ __forceinline__ float fast_exp2(float x) { return __builtin_amdgcn_exp2f(x); }
static __device__ __forceinline__ float fast_rcp(float x)  { return __builtin_amdgcn_rcpf(x); }

// One block, 1024 threads: thread t=(r,s). Computes cc[r]=||c_r||^2, finds d2min over
// r<s, compacts pairs with d2 <= d2min+CUT into plist as (omega, int(r*32+s)).
__global__ __launch_bounds__(1024) void prune_kernel(const float* __restrict__ c,
                                                     float* __restrict__ cc,
                                                     int* __restrict__ npairs,
                                                     float2* __restrict__ plist) {
    __shared__ float red[16];
    __shared__ float dmin_sh;
    __shared__ int cnt;
    const int t = threadIdx.x;
    const int r = t >> 5, s = t & 31;
    const bool active = s > r;

    float d2 = 0.f;
#pragma unroll 8
    for (int d = 0; d < DD; ++d) {
        float diff = c[r * DD + d] - c[s * DD + d];
        d2 = fmaf(diff, diff, d2);
    }
    float dm = active ? d2 : 3.4e38f;
#pragma unroll
    for (int off = 32; off > 0; off >>= 1) dm = fminf(dm, __shfl_down(dm, off, 64));
    if ((t & 63) == 0) red[t >> 6] = dm;
    if (t == 0) cnt = 0;
    __syncthreads();
    if (t < 64) {
        float v = (t < 16) ? red[t] : 3.4e38f;
#pragma unroll
        for (int off = 8; off > 0; off >>= 1) v = fminf(v, __shfl_down(v, off, 64));
        if (t == 0) dmin_sh = v;
    }
    __syncthreads();
    const float dmin = dmin_sh;
    if (active && d2 <= dmin + D2_CUT) {
        int idx = atomicAdd(&cnt, 1);
        plist[idx] = make_float2(fast_exp2(-d2 * LOG2E), __int_as_float(t));
    }
    if (t < RR) {
        float a2 = 0.f;
#pragma unroll 8
        for (int d = 0; d < DD; ++d) { float v = c[t * DD + d]; a2 = fmaf(v, v, a2); }
        cc[t] = a2;
    }
    __syncthreads();
    if (t == 0) *npairs = cnt;
}

__global__ __launch_bounds__(256) void sheaf2_kernel(
    const float* __restrict__ m, const float* __restrict__ w,
    const float* __restrict__ p, const float* __restrict__ c,
    const float* __restrict__ cc, const int* __restrict__ npairs,
    const float2* __restrict__ plist, float* __restrict__ partials) {
    __shared__ float2 sm_cT2[32 * 33];               // 8448 B
    __shared__ float  sm_mass[PP * 36];              // 2304 B (pad 36: 16B-aligned rows)
    __shared__ __align__(16) float2 sm_pl[RR * KK];  // 16384 B: (pbar, pbar*log2 pbar)
    __shared__ float  sm_sw[PP];
    __shared__ float  sred[4];

    const int tid = threadIdx.x;
    const int bt  = blockIdx.x;

    // ---- stage c transposed into LDS ----
    {
        const float2* c2 = (const float2*)c;  // [r][d2], 1024 entries
#pragma unroll
        for (int it = 0; it < 4; ++it) {
            int idx = tid + 256 * it;
            int rr = idx >> 5, d2i = idx & 31;
            sm_cT2[d2i * 33 + rr] = c2[idx];
        }
    }
    __syncthreads();

    // ---- phase 1: logits[p][r] = 2*m.c - ||c||^2  (||m||^2 cancels in softmax) ----
    {
        const int r  = tid & 31;
        const int pg = tid >> 5;  // 0..7; handles pi = pg and pg+8
        const float4* m4a = (const float4*)(m + ((size_t)bt * PP + pg) * DD);
        const float4* m4b = m4a + (8 * DD) / 4;
        float ccr = cc[r];
        float acc0 = 0.f, acc1 = 0.f;
#pragma unroll
        for (int d4 = 0; d4 < 16; ++d4) {
            float2 ca = sm_cT2[(2 * d4) * 33 + r];
            float2 cb = sm_cT2[(2 * d4 + 1) * 33 + r];
            float4 ma = m4a[d4];
            float4 mb = m4b[d4];
            acc0 = fmaf(ma.x, ca.x, acc0); acc0 = fmaf(ma.y, ca.y, acc0);
            acc0 = fmaf(ma.z, cb.x, acc0); acc0 = fmaf(ma.w, cb.y, acc0);
            acc1 = fmaf(mb.x, ca.x, acc1); acc1 = fmaf(mb.y, ca.y, acc1);
            acc1 = fmaf(mb.z, cb.x, acc1); acc1 = fmaf(mb.w, cb.y, acc1);
        }
        sm_mass[pg * 36 + r]       = fmaf(2.f, acc0, -ccr);
        sm_mass[(pg + 8) * 36 + r] = fmaf(2.f, acc1, -ccr);
    }
    __syncthreads();

    // ---- phase 2: per-p softmax over r (exp only; scale deferred), sw = w / sum ----
    if (tid < PP) {
        float4* row4 = (float4*)&sm_mass[tid * 36];
        float4 v[8];
        float mx = -3.4e38f;
#pragma unroll
        for (int i = 0; i < 8; ++i) {
            v[i] = row4[i];
            mx = fmaxf(mx, fmaxf(fmaxf(v[i].x, v[i].y), fmaxf(v[i].z, v[i].w)));
        }
        float ssum = 0.f;
#pragma unroll
        for (int i = 0; i < 8; ++i) {
            v[i].x = fast_exp2((v[i].x - mx) * LOG2E);
            v[i].y = fast_exp2((v[i].y - mx) * LOG2E);
            v[i].z = fast_exp2((v[i].z - mx) * LOG2E);
            v[i].w = fast_exp2((v[i].w - mx) * LOG2E);
            ssum += (v[i].x + v[i].y) + (v[i].z + v[i].w);
            row4[i] = v[i];
        }
        sm_sw[tid] = w[(size_t)bt * PP + tid] * fast_rcp(ssum);
    }
    __syncthreads();

    // ---- phase 3: mass[p][r] = e*sw[p] / (tot_r + eps) ----
    if (tid < RR) {
        float ef[PP];
        float tot = 0.f;
#pragma unroll
        for (int pi = 0; pi < PP; ++pi) {
            ef[pi] = sm_mass[pi * 36 + tid] * sm_sw[pi];
            tot += ef[pi];
        }
        float inv = fast_rcp(tot + 1e-6f);
#pragma unroll
        for (int pi = 0; pi < PP; ++pi) sm_mass[pi * 36 + tid] = ef[pi] * inv;
    }
    __syncthreads();

    // ---- phase 4: pbar[r][k]; store (pb, pb*log2 pb) ----
    {
        const int k  = tid & 63;
        const int wv = tid >> 6;
        const int r0 = wv * 8;
        const float* pg_ = p + (size_t)bt * PP * KK + k;
        float pcol[PP];
#pragma unroll
        for (int pi = 0; pi < PP; ++pi) pcol[pi] = pg_[pi * KK];
        float acc[8] = {0.f, 0.f, 0.f, 0.f, 0.f, 0.f, 0.f, 0.f};
#pragma unroll
        for (int pi = 0; pi < PP; ++pi) {
            float4 ma = *(const float4*)&sm_mass[pi * 36 + r0];
            float4 mb = *(const float4*)&sm_mass[pi * 36 + r0 + 4];
            acc[0] = fmaf(pcol[pi], ma.x, acc[0]);
            acc[1] = fmaf(pcol[pi], ma.y, acc[1]);
            acc[2] = fmaf(pcol[pi], ma.z, acc[2]);
            acc[3] = fmaf(pcol[pi], ma.w, acc[3]);
            acc[4] = fmaf(pcol[pi], mb.x, acc[4]);
            acc[5] = fmaf(pcol[pi], mb.y, acc[5]);
            acc[6] = fmaf(pcol[pi], mb.z, acc[6]);
            acc[7] = fmaf(pcol[pi], mb.w, acc[7]);
        }
#pragma unroll
        for (int j = 0; j < 8; ++j) {
            float pb = acc[j];
            float l2 = fast_log2(pb + 1e-8f);
            sm_pl[(r0 + j) * KK + k] = make_float2(pb, pb * l2);
        }
    }
    __syncthreads();

    // ---- phase 5: sum over PRUNED pairs of omega * [pr*l2pr + ps*l2ps - (pr+ps)*l2(mid)] ----
    {
        const int k  = tid & 63;
        const int wv = __builtin_amdgcn_readfirstlane(tid >> 6);
        const int np = __builtin_amdgcn_readfirstlane(*npairs);
        float acc = 0.f;
        for (int i = wv; i < np; i += 4) {
            float2 e = plist[i];                    // wave-uniform -> s_load
            int rs = __float_as_int(e.y);
            int r = rs >> 5, s = rs & 31;
            float2 a = sm_pl[r * KK + k];
            float2 b = sm_pl[s * KK + k];
            float sum = a.x + b.x;
            float t   = a.y + b.y;
            float lm  = fast_log2(fmaf(0.5f, sum, 1e-8f));
            t = fmaf(-sum, lm, t);
            acc = fmaf(e.x, t, acc);
        }
#pragma unroll
        for (int off = 32; off > 0; off >>= 1) acc += __shfl_down(acc, off, 64);
        if (k == 0) sred[tid >> 6] = acc;
    }
    __syncthreads();
    if (tid == 0) {
        float tot = (sred[0] + sred[1]) + (sred[2] + sred[3]);
        partials[bt] = tot * (0.5f * LN2 / 496.0f);
    }
}

__global__ __launch_bounds__(256) void reduce_kernel(const float* __restrict__ partials,
                                                     float* __restrict__ out) {
    __shared__ float sred[4];
    const int tid = threadIdx.x;
    const float4* p4 = (const float4*)partials;  // 1024 float4
    float acc = 0.f;
#pragma unroll
    for (int i = 0; i < 4; ++i) {
        float4 v = p4[tid + 256 * i];
        acc += (v.x + v.y) + (v.z + v.w);
    }
#pragma unroll
    for (int off = 32; off > 0; off >>= 1) acc += __shfl_down(acc, off, 64);
    if ((tid & 63) == 0) sred[tid >> 6] = acc;
    __syncthreads();
    if (tid == 0) out[0] = (sred[0] + sred[1]) + (sred[2] + sred[3]);
}

extern "C" void kernel_launch(void* const* d_in, const int* in_sizes, int n_in,
                              void* d_out, int out_size, void* d_ws, size_t ws_size,
                              hipStream_t stream) {
    const float* m = (const float*)d_in[0];
    const float* w = (const float*)d_in[1];
    const float* p = (const float*)d_in[2];
    const float* c = (const float*)d_in[3];
    float* out = (float*)d_out;

    float* wsf      = (float*)d_ws;
    int*   npairs   = (int*)d_ws;            // [0]
    float* cc       = wsf + 64;              // 32 floats @ 256 B
    float2* plist   = (float2*)(wsf + 128);  // up to 496 float2 @ 512 B
    float* partials = wsf + 2048;            // 4096 floats @ 8 KB (16B-aligned)

    prune_kernel<<<1, 1024, 0, stream>>>(c, cc, npairs, plist);
    sheaf2_kernel<<<NBT, 256, 0, stream>>>(m, w, p, c, cc, npairs, plist, partials);
    reduce_kernel<<<1, 256, 0, stream>>>(partials, out);
}